// Round 1
// baseline (1423.876 us; speedup 1.0000x reference)
//
#include <hip/hip_runtime.h>
#include <hip/hip_bf16.h>

// Problem constants: x [4,2048,1024] fp32; Wq/Wk/Wv [1024,1024] fp32.
#define NB 4      // batch
#define SB 2048   // sequence
#define DD 1024   // d_in == d_out

__device__ __forceinline__ float bf2f(unsigned short u) {
    return __uint_as_float(((unsigned int)u) << 16);
}

// ---------------------------------------------------------------------------
// Kernel 1: QKV projection. C[8192,1024] = X[8192,1024] @ W[1024,1024].
// blockIdx.z in {0,1,2} selects Wq/Wk/Wv and Q/K/V output. Output bf16.
// 64x64 tile, BK=16, 256 threads, 4x4 micro-tile per thread, fp32 accumulate.
// ---------------------------------------------------------------------------
__global__ __launch_bounds__(256) void qkv_gemm(
    const float* __restrict__ x,
    const float* __restrict__ Wq, const float* __restrict__ Wk,
    const float* __restrict__ Wv,
    __hip_bfloat16* __restrict__ Q, __hip_bfloat16* __restrict__ Ko,
    __hip_bfloat16* __restrict__ V)
{
    const int n0 = blockIdx.x * 64;
    const int m0 = blockIdx.y * 64;  // rows over B*S = 8192
    const float* W = (blockIdx.z == 0) ? Wq : (blockIdx.z == 1) ? Wk : Wv;
    __hip_bfloat16* C = (blockIdx.z == 0) ? Q : (blockIdx.z == 1) ? Ko : V;

    __shared__ float As[16][68];  // [k][m], +4 pad keeps 16B align, spreads banks
    __shared__ float Bs[16][68];  // [k][n]

    const int tid = threadIdx.x;
    const int tx = tid & 15, ty = tid >> 4;
    const int am = tid >> 2, ak = (tid & 3) * 4;   // A loader: 64 rows x 16 k
    const int bk = tid >> 4, bn = (tid & 15) * 4;  // B loader: 16 k x 64 n

    float acc[4][4] = {};
    for (int k0 = 0; k0 < DD; k0 += 16) {
        float4 av = *(const float4*)&x[(size_t)(m0 + am) * DD + k0 + ak];
        float4 bv = *(const float4*)&W[(size_t)(k0 + bk) * DD + n0 + bn];
        As[ak + 0][am] = av.x; As[ak + 1][am] = av.y;
        As[ak + 2][am] = av.z; As[ak + 3][am] = av.w;
        *(float4*)&Bs[bk][bn] = bv;
        __syncthreads();
#pragma unroll
        for (int kk = 0; kk < 16; kk++) {
            float4 a = *(const float4*)&As[kk][ty * 4];
            float4 b = *(const float4*)&Bs[kk][tx * 4];
            float af[4] = {a.x, a.y, a.z, a.w};
            float bf[4] = {b.x, b.y, b.z, b.w};
#pragma unroll
            for (int i = 0; i < 4; i++)
#pragma unroll
                for (int j = 0; j < 4; j++) acc[i][j] += af[i] * bf[j];
        }
        __syncthreads();
    }
#pragma unroll
    for (int i = 0; i < 4; i++) {
        const size_t m = m0 + ty * 4 + i;
#pragma unroll
        for (int j = 0; j < 4; j++)
            C[m * DD + n0 + tx * 4 + j] = __float2bfloat16(acc[i][j]);
    }
}

// ---------------------------------------------------------------------------
// Kernel 2: scores. Sc[b][q][k] = (1/32) * sum_d Q[b][q][d]*K[b][k][d].
// Blocks fully above the causal diagonal are skipped (softmax never reads them).
// ---------------------------------------------------------------------------
__global__ __launch_bounds__(256) void scores_gemm(
    const __hip_bfloat16* __restrict__ Q,
    const __hip_bfloat16* __restrict__ Kc,
    float* __restrict__ Sc)
{
    const int kn0 = blockIdx.x * 64;  // key index tile
    const int qm0 = blockIdx.y * 64;  // query index tile
    if (kn0 > qm0) return;            // entire tile masked
    const int b = blockIdx.z;
    const __hip_bfloat16* Qb = Q + (size_t)b * SB * DD;
    const __hip_bfloat16* Kb = Kc + (size_t)b * SB * DD;
    float* Sb = Sc + (size_t)b * SB * SB;

    __shared__ float As[16][68];  // [d][q]
    __shared__ float Bs[16][68];  // [d][k]

    const int tid = threadIdx.x;
    const int tx = tid & 15, ty = tid >> 4;
    const int am = tid >> 2, ad = (tid & 3) * 4;  // 64 rows x 16 d, both tiles

    float acc[4][4] = {};
    for (int d0 = 0; d0 < DD; d0 += 16) {
        ushort4 aq = *(const ushort4*)&Qb[(size_t)(qm0 + am) * DD + d0 + ad];
        ushort4 bk = *(const ushort4*)&Kb[(size_t)(kn0 + am) * DD + d0 + ad];
        As[ad + 0][am] = bf2f(aq.x); As[ad + 1][am] = bf2f(aq.y);
        As[ad + 2][am] = bf2f(aq.z); As[ad + 3][am] = bf2f(aq.w);
        Bs[ad + 0][am] = bf2f(bk.x); Bs[ad + 1][am] = bf2f(bk.y);
        Bs[ad + 2][am] = bf2f(bk.z); Bs[ad + 3][am] = bf2f(bk.w);
        __syncthreads();
#pragma unroll
        for (int kk = 0; kk < 16; kk++) {
            float4 a = *(const float4*)&As[kk][ty * 4];
            float4 b = *(const float4*)&Bs[kk][tx * 4];
            float af[4] = {a.x, a.y, a.z, a.w};
            float bf[4] = {b.x, b.y, b.z, b.w};
#pragma unroll
            for (int i = 0; i < 4; i++)
#pragma unroll
                for (int j = 0; j < 4; j++) acc[i][j] += af[i] * bf[j];
        }
        __syncthreads();
    }
    const float scale = 0.03125f;  // 1/sqrt(1024)
#pragma unroll
    for (int i = 0; i < 4; i++) {
        const size_t q = qm0 + ty * 4 + i;
#pragma unroll
        for (int j = 0; j < 4; j++)
            Sb[q * SB + kn0 + tx * 4 + j] = acc[i][j] * scale;
    }
}

// ---------------------------------------------------------------------------
// Kernel 3: causal softmax, in place. One block (256 thr) per row; 8 elems/thr.
// Reads only j<=i (computed region); writes full row with zeros for j>i.
// ---------------------------------------------------------------------------
__global__ __launch_bounds__(256) void softmax_kernel(float* __restrict__ Sc)
{
    const int row = blockIdx.x;      // 0 .. B*S-1
    const int b = row >> 11;
    const int i = row & (SB - 1);
    float* r = Sc + ((size_t)b * SB + i) * SB;
    const int t = threadIdx.x;
    const int lane = t & 63, wave = t >> 6;
    __shared__ float red[8];

    float v[8];
    float mx = -1e30f;
#pragma unroll
    for (int c = 0; c < 8; c++) {
        const int j = c * 256 + t;
        const float s = (j <= i) ? r[j] : -1e30f;
        v[c] = s;
        mx = fmaxf(mx, s);
    }
#pragma unroll
    for (int o = 32; o > 0; o >>= 1) mx = fmaxf(mx, __shfl_down(mx, o));
    if (lane == 0) red[wave] = mx;
    __syncthreads();
    mx = fmaxf(fmaxf(red[0], red[1]), fmaxf(red[2], red[3]));

    float sum = 0.f;
#pragma unroll
    for (int c = 0; c < 8; c++) {
        const int j = c * 256 + t;
        const float e = (j <= i) ? __expf(v[c] - mx) : 0.f;
        v[c] = e;
        sum += e;
    }
#pragma unroll
    for (int o = 32; o > 0; o >>= 1) sum += __shfl_down(sum, o);
    if (lane == 0) red[4 + wave] = sum;  // disjoint slots from red[0..3]
    __syncthreads();
    const float inv = 1.0f / (red[4] + red[5] + red[6] + red[7]);
#pragma unroll
    for (int c = 0; c < 8; c++) r[c * 256 + t] = v[c] * inv;
}

// ---------------------------------------------------------------------------
// Kernel 4: O[b][q][n] = sum_k P[b][q][k] * V[b][k][n]. K-loop stops at
// qm0+64 (P is zero beyond the diagonal). Output fp32 to d_out.
// ---------------------------------------------------------------------------
__global__ __launch_bounds__(256) void pv_gemm(
    const float* __restrict__ P, const __hip_bfloat16* __restrict__ V,
    float* __restrict__ O)
{
    const int n0 = blockIdx.x * 64;
    const int qm0 = blockIdx.y * 64;
    const int b = blockIdx.z;
    const float* Pb = P + (size_t)b * SB * SB;
    const __hip_bfloat16* Vb = V + (size_t)b * SB * DD;
    float* Ob = O + (size_t)b * SB * DD;

    __shared__ float As[16][68];  // [k][q]
    __shared__ float Bs[16][68];  // [k][n]

    const int tid = threadIdx.x;
    const int tx = tid & 15, ty = tid >> 4;
    const int am = tid >> 2, ak = (tid & 3) * 4;
    const int bk = tid >> 4, bn = (tid & 15) * 4;

    float acc[4][4] = {};
    const int kend = qm0 + 64;  // causal truncation
    for (int k0 = 0; k0 < kend; k0 += 16) {
        float4 av = *(const float4*)&Pb[(size_t)(qm0 + am) * SB + k0 + ak];
        ushort4 bv = *(const ushort4*)&Vb[(size_t)(k0 + bk) * DD + n0 + bn];
        As[ak + 0][am] = av.x; As[ak + 1][am] = av.y;
        As[ak + 2][am] = av.z; As[ak + 3][am] = av.w;
        float4 bf4 = make_float4(bf2f(bv.x), bf2f(bv.y), bf2f(bv.z), bf2f(bv.w));
        *(float4*)&Bs[bk][bn] = bf4;
        __syncthreads();
#pragma unroll
        for (int kk = 0; kk < 16; kk++) {
            float4 a = *(const float4*)&As[kk][ty * 4];
            float4 b2 = *(const float4*)&Bs[kk][tx * 4];
            float af[4] = {a.x, a.y, a.z, a.w};
            float bf[4] = {b2.x, b2.y, b2.z, b2.w};
#pragma unroll
            for (int i = 0; i < 4; i++)
#pragma unroll
                for (int j = 0; j < 4; j++) acc[i][j] += af[i] * bf[j];
        }
        __syncthreads();
    }
#pragma unroll
    for (int i = 0; i < 4; i++) {
        const size_t q = qm0 + ty * 4 + i;
#pragma unroll
        for (int j = 0; j < 4; j++)
            Ob[q * DD + n0 + tx * 4 + j] = acc[i][j];
    }
}

extern "C" void kernel_launch(void* const* d_in, const int* in_sizes, int n_in,
                              void* d_out, int out_size, void* d_ws, size_t ws_size,
                              hipStream_t stream)
{
    const float* x  = (const float*)d_in[0];
    const float* Wq = (const float*)d_in[1];
    const float* Wk = (const float*)d_in[2];
    const float* Wv = (const float*)d_in[3];
    float* out = (float*)d_out;

    // ws layout: Q,K,V bf16 [B*S*D] each (16.78 MB each), then Sc fp32
    // [B*S*S] (67.1 MB). Total 117.4 MB.
    __hip_bfloat16* Q = (__hip_bfloat16*)d_ws;
    __hip_bfloat16* K = Q + (size_t)NB * SB * DD;
    __hip_bfloat16* V = K + (size_t)NB * SB * DD;
    float* Sc = (float*)(V + (size_t)NB * SB * DD);

    qkv_gemm<<<dim3(DD / 64, (NB * SB) / 64, 3), 256, 0, stream>>>(
        x, Wq, Wk, Wv, Q, K, V);
    scores_gemm<<<dim3(SB / 64, SB / 64, NB), 256, 0, stream>>>(Q, K, Sc);
    softmax_kernel<<<dim3(NB * SB), 256, 0, stream>>>(Sc);
    pv_gemm<<<dim3(DD / 64, SB / 64, NB), 256, 0, stream>>>(Sc, V, out);
}

// Round 2
// 284.367 us; speedup vs baseline: 5.0072x; 5.0072x over previous
//
#include <hip/hip_runtime.h>
#include <hip/hip_bf16.h>

// x [4,2048,1024] fp32; Wq/Wk/Wv [1024,1024] fp32. Causal attention.
#define NB 4
#define SB 2048
#define DD 1024
#define BM 128
#define BN 128
#define BK 32

typedef __attribute__((ext_vector_type(8))) short bf16x8;
typedef __attribute__((ext_vector_type(4))) float f32x4;
typedef unsigned int u32;

__device__ __forceinline__ float bf2f(unsigned short u) {
    return __uint_as_float(((u32)u) << 16);
}
__device__ __forceinline__ short f2bf(float f) {
    u32 u = __float_as_uint(f);
    u32 r = (u + 0x7fffu + ((u >> 16) & 1u)) >> 16;
    return (short)r;
}

// ---------------------------------------------------------------------------
// cast x fp32 -> bf16, 8 elems/thread
// ---------------------------------------------------------------------------
__global__ __launch_bounds__(256) void cast_x(const float* __restrict__ x,
                                              short* __restrict__ xb) {
    const size_t i = ((size_t)blockIdx.x * 256 + threadIdx.x) * 8;
    float4 a = *(const float4*)&x[i];
    float4 b = *(const float4*)&x[i + 4];
    bf16x8 o;
    o[0] = f2bf(a.x); o[1] = f2bf(a.y); o[2] = f2bf(a.z); o[3] = f2bf(a.w);
    o[4] = f2bf(b.x); o[5] = f2bf(b.y); o[6] = f2bf(b.z); o[7] = f2bf(b.w);
    *(bf16x8*)&xb[i] = o;
}

// ---------------------------------------------------------------------------
// cast + transpose W: Wt[z][n][k] = W[z][k][n], bf16. 64x64 LDS tile.
// ---------------------------------------------------------------------------
__global__ __launch_bounds__(256) void castw_t(
    const float* __restrict__ Wq, const float* __restrict__ Wk,
    const float* __restrict__ Wv, short* __restrict__ Wt)
{
    const int z = blockIdx.z;
    const float* W = (z == 0) ? Wq : (z == 1) ? Wk : Wv;
    short* T = Wt + (size_t)z * DD * DD;
    __shared__ short t[64][65];
    const int k0 = blockIdx.x * 64;
    const int n0 = blockIdx.y * 64;
    const int tid = threadIdx.x;
    {
        const int r = tid >> 4;
        const int c = (tid & 15) * 4;
#pragma unroll
        for (int i = 0; i < 4; i++) {
            float4 v = *(const float4*)&W[(size_t)(k0 + i * 16 + r) * DD + n0 + c];
            t[i * 16 + r][c + 0] = f2bf(v.x);
            t[i * 16 + r][c + 1] = f2bf(v.y);
            t[i * 16 + r][c + 2] = f2bf(v.z);
            t[i * 16 + r][c + 3] = f2bf(v.w);
        }
    }
    __syncthreads();
    {
        const int r = tid >> 3;
        const int c = (tid & 7) * 8;
#pragma unroll
        for (int i = 0; i < 2; i++) {
            bf16x8 o;
#pragma unroll
            for (int j = 0; j < 8; j++) o[j] = t[c + j][i * 32 + r];
            *(bf16x8*)&T[(size_t)(n0 + i * 32 + r) * DD + k0 + c] = o;
        }
    }
}

// ---------------------------------------------------------------------------
// transpose V bf16: Vt[b][d][s] = V[b][s][d]. 64x64 LDS tile.
// ---------------------------------------------------------------------------
__global__ __launch_bounds__(256) void transpose_v(const short* __restrict__ V,
                                                   short* __restrict__ Vt)
{
    __shared__ short t[64][65];
    const int b = blockIdx.z;
    const int s0 = blockIdx.x * 64;
    const int d0 = blockIdx.y * 64;
    const short* Vb = V + (size_t)b * SB * DD;
    short* Tb = Vt + (size_t)b * DD * SB;
    const int tid = threadIdx.x;
    const int r = tid >> 3;
    const int c = (tid & 7) * 8;
#pragma unroll
    for (int i = 0; i < 2; i++) {
        bf16x8 v = *(const bf16x8*)&Vb[(size_t)(s0 + i * 32 + r) * DD + d0 + c];
#pragma unroll
        for (int j = 0; j < 8; j++) t[i * 32 + r][c + j] = v[j];
    }
    __syncthreads();
#pragma unroll
    for (int i = 0; i < 2; i++) {
        bf16x8 o;
#pragma unroll
        for (int j = 0; j < 8; j++) o[j] = t[c + j][i * 32 + r];
        *(bf16x8*)&Tb[(size_t)(d0 + i * 32 + r) * SB + s0 + c] = o;
    }
}

// ---------------------------------------------------------------------------
// Shared MFMA GEMM machinery: C[128x128] = A[128xK] * Bt[128xK]^T
// m97 structure: BK=32, 256 thr (4 waves, 2x2 of 64x64), global_load_lds x16B.
// ---------------------------------------------------------------------------
__device__ __forceinline__ void stage128x32(const short* __restrict__ g, int ld,
                                            short* lds, int tid) {
    const int wave = tid >> 6, lane = tid & 63;
    const int r = lane >> 2;        // 16 rows per 1KB chunk
    const int c = (lane & 3) * 8;   // 4 x 8 bf16 = 64B per row
#pragma unroll
    for (int i = 0; i < 2; i++) {
        const int chunk = wave * 2 + i;
        const short* gp = g + (size_t)(chunk * 16 + r) * ld + c;
        __builtin_amdgcn_global_load_lds(
            (const __attribute__((address_space(1))) u32*)gp,
            (__attribute__((address_space(3))) u32*)(lds + chunk * 512 + lane * 8),
            16, 0, 0);
    }
}

__device__ __forceinline__ void gemm_bt_body(
    const short* __restrict__ A, int lda, const short* __restrict__ Bt, int ldb,
    int m0, int n0, int kend, short* As, short* Bs, f32x4 (&acc)[4][4], int tid)
{
    const int lane = tid & 63;
    const int wave = tid >> 6;
    const int wm = (wave >> 1) * 64, wn = (wave & 1) * 64;
    const int fr = lane & 15;       // fragment row (m or n within 16)
    const int quad = lane >> 4;     // k-chunk selector
    for (int k0 = 0; k0 < kend; k0 += BK) {
        stage128x32(A + (size_t)m0 * lda + k0, lda, As, tid);
        stage128x32(Bt + (size_t)n0 * ldb + k0, ldb, Bs, tid);
        __syncthreads();
        bf16x8 af[4], bf[4];
#pragma unroll
        for (int t = 0; t < 4; t++) {
            af[t] = *(const bf16x8*)&As[(wm + t * 16 + fr) * BK + quad * 8];
            bf[t] = *(const bf16x8*)&Bs[(wn + t * 16 + fr) * BK + quad * 8];
        }
#pragma unroll
        for (int mt = 0; mt < 4; mt++)
#pragma unroll
            for (int nt = 0; nt < 4; nt++)
                acc[mt][nt] = __builtin_amdgcn_mfma_f32_16x16x32_bf16(
                    af[mt], bf[nt], acc[mt][nt], 0, 0, 0);
        __syncthreads();
    }
}

// ---------------------------------------------------------------------------
// QKV projection: C = xb @ W  (via Wt = W^T), output bf16 Q/K/V.
// ---------------------------------------------------------------------------
__global__ __launch_bounds__(256) void qkv_mfma(
    const short* __restrict__ xb, const short* __restrict__ Wt,
    short* __restrict__ Q, short* __restrict__ K, short* __restrict__ V)
{
    __shared__ short As[BM * BK], Bs[BN * BK];
    const int n0 = blockIdx.x * BN;
    const int m0 = blockIdx.y * BM;
    const int z = blockIdx.z;
    const short* B = Wt + (size_t)z * DD * DD;
    short* C = (z == 0) ? Q : (z == 1) ? K : V;
    f32x4 acc[4][4];
#pragma unroll
    for (int a = 0; a < 4; a++)
#pragma unroll
        for (int b = 0; b < 4; b++) acc[a][b] = (f32x4){0.f, 0.f, 0.f, 0.f};
    gemm_bt_body(xb, DD, B, DD, m0, n0, DD, As, Bs, acc, threadIdx.x);
    const int lane = threadIdx.x & 63, wave = threadIdx.x >> 6;
    const int wm = (wave >> 1) * 64, wn = (wave & 1) * 64;
    const int fr = lane & 15, quad = lane >> 4;
#pragma unroll
    for (int mt = 0; mt < 4; mt++)
#pragma unroll
        for (int nt = 0; nt < 4; nt++)
#pragma unroll
            for (int r = 0; r < 4; r++) {
                const size_t m = m0 + wm + mt * 16 + quad * 4 + r;
                const size_t n = n0 + wn + nt * 16 + fr;
                C[m * DD + n] = f2bf(acc[mt][nt][r]);
            }
}

// ---------------------------------------------------------------------------
// Scores: Sc[b][q][k] = scale * Q_b[q,:] . K_b[k,:], fp32 out, causal skip.
// ---------------------------------------------------------------------------
__global__ __launch_bounds__(256) void scores_mfma(
    const short* __restrict__ Q, const short* __restrict__ Kc,
    float* __restrict__ Sc)
{
    const int kn0 = blockIdx.x * BN;
    const int qm0 = blockIdx.y * BM;
    if (kn0 > qm0) return;  // tile fully above the diagonal
    const int b = blockIdx.z;
    __shared__ short As[BM * BK], Bs[BN * BK];
    const short* Qb = Q + (size_t)b * SB * DD;
    const short* Kb = Kc + (size_t)b * SB * DD;
    float* Sb = Sc + (size_t)b * SB * SB;
    f32x4 acc[4][4];
#pragma unroll
    for (int a = 0; a < 4; a++)
#pragma unroll
        for (int c = 0; c < 4; c++) acc[a][c] = (f32x4){0.f, 0.f, 0.f, 0.f};
    gemm_bt_body(Qb, DD, Kb, DD, qm0, kn0, DD, As, Bs, acc, threadIdx.x);
    const int lane = threadIdx.x & 63, wave = threadIdx.x >> 6;
    const int wm = (wave >> 1) * 64, wn = (wave & 1) * 64;
    const int fr = lane & 15, quad = lane >> 4;
    const float scale = 0.03125f;  // 1/sqrt(1024)
#pragma unroll
    for (int mt = 0; mt < 4; mt++)
#pragma unroll
        for (int nt = 0; nt < 4; nt++)
#pragma unroll
            for (int r = 0; r < 4; r++) {
                const size_t q = qm0 + wm + mt * 16 + quad * 4 + r;
                const size_t k = kn0 + wn + nt * 16 + fr;
                Sb[q * SB + k] = acc[mt][nt][r] * scale;
            }
}

// ---------------------------------------------------------------------------
// Causal softmax. Reads fp32 row (j<=i only); writes bf16 P into the FIRST
// HALF of the same row (in-place, stride 4096 shorts). Zeros for j>i.
// All global reads precede the first __syncthreads; writes follow the last.
// ---------------------------------------------------------------------------
__global__ __launch_bounds__(256) void softmax_kernel(float* __restrict__ Sc)
{
    const int row = blockIdx.x;      // b*SB + i
    const int i = row & (SB - 1);
    float* r = Sc + (size_t)row * SB;
    short* p = (short*)r;            // bf16 P row, first half of fp32 row
    const int t = threadIdx.x;
    const int lane = t & 63, wave = t >> 6;
    __shared__ float red[8];

    float v[8];
    float mx = -1e30f;
#pragma unroll
    for (int c = 0; c < 8; c++) {
        const int j = c * 256 + t;
        const float s = (j <= i) ? r[j] : -1e30f;
        v[c] = s;
        mx = fmaxf(mx, s);
    }
#pragma unroll
    for (int o = 32; o > 0; o >>= 1) mx = fmaxf(mx, __shfl_down(mx, o));
    if (lane == 0) red[wave] = mx;
    __syncthreads();
    mx = fmaxf(fmaxf(red[0], red[1]), fmaxf(red[2], red[3]));

    float sum = 0.f;
#pragma unroll
    for (int c = 0; c < 8; c++) {
        const int j = c * 256 + t;
        const float e = (j <= i) ? __expf(v[c] - mx) : 0.f;
        v[c] = e;
        sum += e;
    }
#pragma unroll
    for (int o = 32; o > 0; o >>= 1) sum += __shfl_down(sum, o);
    if (lane == 0) red[4 + wave] = sum;
    __syncthreads();
    const float inv = 1.0f / (red[4] + red[5] + red[6] + red[7]);
#pragma unroll
    for (int c = 0; c < 8; c++) p[c * 256 + t] = f2bf(v[c] * inv);
}

// ---------------------------------------------------------------------------
// PV: O[b][q][n] = sum_k P[b][q][k] * Vt[b][n][k]. P row stride 4096 shorts.
// K-loop truncated at qm0+BM (P zero above diagonal). fp32 out.
// ---------------------------------------------------------------------------
__global__ __launch_bounds__(256) void pv_mfma(
    const short* __restrict__ P, const short* __restrict__ Vt,
    float* __restrict__ O)
{
    __shared__ short As[BM * BK], Bs[BN * BK];
    const int n0 = blockIdx.x * BN;
    const int qm0 = blockIdx.y * BM;
    const int b = blockIdx.z;
    const short* Pb = P + (size_t)b * SB * (2 * SB);  // fp32 rows reinterpreted
    const short* Vb = Vt + (size_t)b * DD * SB;
    float* Ob = O + (size_t)b * SB * DD;
    f32x4 acc[4][4];
#pragma unroll
    for (int a = 0; a < 4; a++)
#pragma unroll
        for (int c = 0; c < 4; c++) acc[a][c] = (f32x4){0.f, 0.f, 0.f, 0.f};
    gemm_bt_body(Pb, 2 * SB, Vb, SB, qm0, n0, qm0 + BM, As, Bs, acc, threadIdx.x);
    const int lane = threadIdx.x & 63, wave = threadIdx.x >> 6;
    const int wm = (wave >> 1) * 64, wn = (wave & 1) * 64;
    const int fr = lane & 15, quad = lane >> 4;
#pragma unroll
    for (int mt = 0; mt < 4; mt++)
#pragma unroll
        for (int nt = 0; nt < 4; nt++)
#pragma unroll
            for (int r = 0; r < 4; r++) {
                const size_t q = qm0 + wm + mt * 16 + quad * 4 + r;
                const size_t n = n0 + wn + nt * 16 + fr;
                Ob[q * DD + n] = acc[mt][nt][r];
            }
}

extern "C" void kernel_launch(void* const* d_in, const int* in_sizes, int n_in,
                              void* d_out, int out_size, void* d_ws, size_t ws_size,
                              hipStream_t stream)
{
    const float* x  = (const float*)d_in[0];
    const float* Wq = (const float*)d_in[1];
    const float* Wk = (const float*)d_in[2];
    const float* Wv = (const float*)d_in[3];
    float* out = (float*)d_out;

    // ws layout (117.44 MB total, same as round 1):
    //   [Q 16.78M][K 16.78M][Vt 16.78M][R 67.1M]
    //   R hosts {V, xb, Wt} during cast/qkv/transpose, then Sc fp32 (+ in-place
    //   bf16 P in the first half of each Sc row) from scores onward.
    const size_t QKV_ELEMS = (size_t)NB * SB * DD;  // 8.39M
    short* Q  = (short*)d_ws;
    short* K  = Q + QKV_ELEMS;
    short* Vt = K + QKV_ELEMS;
    char*  R  = (char*)(Vt + QKV_ELEMS);
    short* V  = (short*)R;
    short* xb = V + QKV_ELEMS;
    short* Wt = xb + QKV_ELEMS;
    float* Sc = (float*)R;        // overlaps V/xb/Wt (dead by then)
    short* P  = (short*)R;        // in-place bf16, row stride 2*SB shorts

    cast_x<<<dim3((unsigned)(QKV_ELEMS / 8 / 256)), 256, 0, stream>>>(x, xb);
    castw_t<<<dim3(DD / 64, DD / 64, 3), 256, 0, stream>>>(Wq, Wk, Wv, Wt);
    qkv_mfma<<<dim3(DD / BN, (NB * SB) / BM, 3), 256, 0, stream>>>(xb, Wt, Q, K, V);
    transpose_v<<<dim3(SB / 64, DD / 64, NB), 256, 0, stream>>>(V, Vt);
    scores_mfma<<<dim3(SB / BN, SB / BM, NB), 256, 0, stream>>>(Q, K, Sc);
    softmax_kernel<<<dim3(NB * SB), 256, 0, stream>>>(Sc);
    pv_mfma<<<dim3(DD / BN, SB / BM, NB), 256, 0, stream>>>(P, Vt, out);
}